// Round 8
// baseline (2369.412 us; speedup 1.0000x reference)
//
#include <hip/hip_runtime.h>
#include <hip/hip_bf16.h>

#define TT 2048
#define BB 32
#define DD 256
#define HH 256
#define GG 768   // 3*H

// weight split (in 8-k groups of uint4): 10 VGPR + 11 LDS + 11 streamed = 32
#define NREG 10
#define NLDS 11
#define NSTR 11

typedef _Float16 half2_t __attribute__((ext_vector_type(2)));
typedef unsigned int u32x4v __attribute__((ext_vector_type(4)));

__device__ inline float fdot2(unsigned int w, unsigned int h, float acc) {
#if __has_builtin(__builtin_amdgcn_fdot2)
    return __builtin_amdgcn_fdot2(__builtin_bit_cast(half2_t, w),
                                  __builtin_bit_cast(half2_t, h), acc, false);
#else
    half2_t a = __builtin_bit_cast(half2_t, w);
    half2_t b = __builtin_bit_cast(half2_t, h);
    return acc + (float)a.x * (float)b.x + (float)a.y * (float)b.y;
#endif
}

// ---------- helpers for fp32/bf16 workspace storage of gi ----------
__device__ inline void store4(float* p, float a, float b, float c, float d) {
    *(float4*)p = make_float4(a, b, c, d);
}
__device__ inline void store4(__hip_bfloat16* p, float a, float b, float c, float d) {
    p[0] = __float2bfloat16(a);
    p[1] = __float2bfloat16(b);
    p[2] = __float2bfloat16(c);
    p[3] = __float2bfloat16(d);
}
__device__ inline float ldgi(const float* p) { return *p; }
__device__ inline float ldgi(const __hip_bfloat16* p) { return __bfloat162float(*p); }

// ---------- pack w_hh [768][256] f32 -> wq4 [32][768] of uint4 ----------
// u32 index i = (g*768 + j)*4 + c  ->  col=j, k = g*8 + 2c (f16 pair {k,k+1})
__global__ __launch_bounds__(256)
void pack_w(const float* __restrict__ w, unsigned int* __restrict__ wf) {
    int i = blockIdx.x * 256 + threadIdx.x;  // 0 .. 98303
    int c  = i & 3;
    int e  = i >> 2;          // g*768 + j
    int g  = e / GG;
    int j  = e - g * GG;
    int k  = g * 8 + 2 * c;
    float a = w[(size_t)j * DD + k];
    float b = w[(size_t)j * DD + k + 1];
    half2_t h = {(_Float16)a, (_Float16)b};
    wf[i] = __builtin_bit_cast(unsigned int, h);
}

// ---------- gi = seq @ w_ih^T + b_ih ; M=65536, N=768, K=256 ----------
template <typename GiT>
__global__ __launch_bounds__(256)
void gemm_gi(const float* __restrict__ A,     // [M][256]
             const float* __restrict__ W,     // [768][256]
             const float* __restrict__ bias,  // [768]
             GiT* __restrict__ C)              // [M][768]
{
    __shared__ float As[32][68];
    __shared__ float Ws[32][68];
    const int tid = threadIdx.x;
    const int bm = blockIdx.y * 64;
    const int bn = blockIdx.x * 64;
    const int tm = (tid & 15) * 4;
    const int tn = (tid >> 4) * 4;
    const int r  = tid >> 3;
    const int c4 = (tid & 7) * 4;

    float acc[4][4] = {};

    for (int k0 = 0; k0 < 256; k0 += 32) {
#pragma unroll
        for (int rr = 0; rr < 64; rr += 32) {
            float4 a = *(const float4*)&A[(size_t)(bm + r + rr) * 256 + k0 + c4];
            As[c4 + 0][r + rr] = a.x;
            As[c4 + 1][r + rr] = a.y;
            As[c4 + 2][r + rr] = a.z;
            As[c4 + 3][r + rr] = a.w;
            float4 w = *(const float4*)&W[(size_t)(bn + r + rr) * 256 + k0 + c4];
            Ws[c4 + 0][r + rr] = w.x;
            Ws[c4 + 1][r + rr] = w.y;
            Ws[c4 + 2][r + rr] = w.z;
            Ws[c4 + 3][r + rr] = w.w;
        }
        __syncthreads();
#pragma unroll
        for (int kk = 0; kk < 32; ++kk) {
            float4 a = *(const float4*)&As[kk][tm];
            float4 w = *(const float4*)&Ws[kk][tn];
            float av[4] = {a.x, a.y, a.z, a.w};
            float wv[4] = {w.x, w.y, w.z, w.w};
#pragma unroll
            for (int i = 0; i < 4; ++i)
#pragma unroll
                for (int j = 0; j < 4; ++j)
                    acc[i][j] += av[i] * wv[j];
        }
        __syncthreads();
    }
#pragma unroll
    for (int i = 0; i < 4; ++i) {
        GiT* cp = C + (size_t)(bm + tm + i) * GG + bn + tn;
        store4(cp, acc[i][0] + bias[bn + tn + 0],
                   acc[i][1] + bias[bn + tn + 1],
                   acc[i][2] + bias[bn + tn + 2],
                   acc[i][3] + bias[bn + tn + 3]);
    }
}

// ---------- sequential scan: 1 wg (768 thr) per batch row, mask-skip -------
// Weight residency, three ways (per column of 128 u32):
//   groups  0..9  -> VGPRs (40 regs; budget is now honestly 170 because the
//                    135KB LDS caps occupancy at 1 block/CU, removing the
//                    allocator's 2-blocks/CU spill incentive seen in r2-r7)
//   groups 10..20 -> LDS, layout [g][j] (consecutive lanes -> consecutive
//                    addresses, conflict-free ds_read_b128)
//   groups 21..31 -> streamed from L2 each step (135KB/step ~ 1200cyc at the
//                    ~111B/cyc port BW measured in r4), loads issued at loop
//                    top, consumed at the GEMV tail.
template <typename GiT>
__global__ __launch_bounds__(768, 3)
void gru_scan(const GiT* __restrict__ gi,        // [T*B][768]
              const int* __restrict__ mask,       // [T*B]
              const float* __restrict__ h0,       // [B][256]
              const uint4* __restrict__ wq4,      // [32][768] (see pack_w)
              const float* __restrict__ b_hh,     // [768]
              float* __restrict__ out,            // [T*B][256]
              float* __restrict__ hfin)           // [B][256]
{
    const int b = blockIdx.x;
    const int j = threadIdx.x;  // 0..767
    __shared__ uint4 wlds[NLDS][GG];              // 135168 B
    __shared__ float gh_lds[GG];                  // 3072 B
    __shared__ __align__(16) _Float16 hhalf[HH];  // 512 B
    __shared__ unsigned long long mbits[TT / 64]; // 256 B

    // --- one-time: mask -> bitmask ---
    if (j < TT / 64) {
        unsigned long long v = 0;
        for (int s = 0; s < 64; ++s)
            v |= (mask[(j * 64 + s) * BB + b] ? 1ull : 0ull) << s;
        mbits[j] = v;
    }

    // --- one-time: VGPR-resident weight groups 0..NREG-1 ---
    u32x4v wreg[NREG];
#pragma unroll
    for (int g = 0; g < NREG; ++g)
        wreg[g] = __builtin_bit_cast(u32x4v, wq4[(size_t)g * GG + j]);

    // --- one-time: LDS-resident weight groups NREG..NREG+NLDS-1 ---
#pragma unroll
    for (int g = 0; g < NLDS; ++g)
        wlds[g][j] = wq4[(size_t)(NREG + g) * GG + j];

    float h_r = 0.f;
    if (j < HH) {
        h_r = h0[b * HH + j];
        hhalf[j] = (_Float16)h_r;
    }
    const float bhh = b_hh[j];
    __syncthreads();

    const uint4* hu4 = (const uint4*)hhalf;            // 32 x uint4
    const uint4* wstr = wq4 + (size_t)(NREG + NLDS) * GG + j;

    for (int ts = 0; ts < TT; ++ts) {
        if ((mbits[ts >> 6] >> (ts & 63)) & 1ull) {
            // gi loads first (consumed after the barrier, longest cover)
            float ir = 0.f, iz = 0.f, inn = 0.f;
            if (j < HH) {
                const GiT* gtb = gi + ((size_t)ts * BB + b) * GG;
                ir  = ldgi(gtb + j);
                iz  = ldgi(gtb + j + HH);
                inn = ldgi(gtb + j + 2 * HH);
            }

            // streamed weight loads issued now, consumed at the GEMV tail
            uint4 wst[NSTR];
#pragma unroll
            for (int g = 0; g < NSTR; ++g)
                wst[g] = wstr[(size_t)g * GG];

            // --- GEMV: gh[j] = b_hh[j] + sum_k w_hh[j][k] * h[k] ---
            float a0 = bhh, a1 = 0.f, a2 = 0.f, a3 = 0.f;
#pragma unroll
            for (int g = 0; g < NREG; ++g) {      // VGPR part
                uint4 hv = hu4[g];                 // uniform -> broadcast
                a0 = fdot2(wreg[g].x, hv.x, a0);
                a1 = fdot2(wreg[g].y, hv.y, a1);
                a2 = fdot2(wreg[g].z, hv.z, a2);
                a3 = fdot2(wreg[g].w, hv.w, a3);
            }
#pragma unroll
            for (int g = 0; g < NLDS; ++g) {      // LDS part
                uint4 hv = hu4[NREG + g];
                uint4 wv = wlds[g][j];             // conflict-free b128
                a0 = fdot2(wv.x, hv.x, a0);
                a1 = fdot2(wv.y, hv.y, a1);
                a2 = fdot2(wv.z, hv.z, a2);
                a3 = fdot2(wv.w, hv.w, a3);
            }
#pragma unroll
            for (int g = 0; g < NSTR; ++g) {      // streamed part
                uint4 hv = hu4[NREG + NLDS + g];
                a0 = fdot2(wst[g].x, hv.x, a0);
                a1 = fdot2(wst[g].y, hv.y, a1);
                a2 = fdot2(wst[g].z, hv.z, a2);
                a3 = fdot2(wst[g].w, hv.w, a3);
            }
            gh_lds[j] = (a0 + a1) + (a2 + a3);
            __syncthreads();  // gh visible; hhalf reads done

            if (j < HH) {
                float hr = gh_lds[j];
                float hz = gh_lds[j + HH];
                float hn = gh_lds[j + 2 * HH];
                float r = 1.f / (1.f + __expf(-(ir + hr)));
                float z = 1.f / (1.f + __expf(-(iz + hz)));
                float e = __expf(2.f * (inn + r * hn));
                float n = 1.f - 2.f / (e + 1.f);
                float ht = (1.f - z) * n + z * h_r;
                out[((size_t)ts * BB + b) * HH + j] = ht;
                h_r = ht;
                hhalf[j] = (_Float16)ht;
            }
            __syncthreads();  // h update visible before next GEMV
        } else {
            // masked: h unchanged, output row exactly zero; no barriers
            // (branch is block-uniform)
            if (j < HH)
                out[((size_t)ts * BB + b) * HH + j] = 0.f;
        }
    }
    if (j < HH) hfin[b * HH + j] = h_r;
}

extern "C" void kernel_launch(void* const* d_in, const int* in_sizes, int n_in,
                              void* d_out, int out_size, void* d_ws, size_t ws_size,
                              hipStream_t stream) {
    const float* seq  = (const float*)d_in[0];
    const int*   mask = (const int*)  d_in[1];
    const float* h0   = (const float*)d_in[2];
    const float* w_ih = (const float*)d_in[3];
    const float* w_hh = (const float*)d_in[4];
    const float* b_ih = (const float*)d_in[5];
    const float* b_hh = (const float*)d_in[6];

    float* out  = (float*)d_out;
    float* hfin = out + (size_t)TT * BB * HH;

    // workspace layout: [wq4: 32*768 uint4][gi: T*B*768 f32 (or bf16)]
    const size_t w_u32 = (size_t)128 * GG;  // 98304 u32
    unsigned int* wf = (unsigned int*)d_ws;
    const size_t gi_elems = (size_t)TT * BB * GG;
    const size_t need_f32 = w_u32 * 4 + gi_elems * 4;

    pack_w<<<(int)(w_u32 / 256), 256, 0, stream>>>(w_hh, wf);

    dim3 ggrid(GG / 64, (TT * BB) / 64);
    if (ws_size >= need_f32) {
        float* gip = (float*)d_ws + w_u32;
        gemm_gi<float><<<ggrid, 256, 0, stream>>>(seq, w_ih, b_ih, gip);
        gru_scan<float><<<BB, GG, 0, stream>>>(gip, mask, h0, (const uint4*)wf,
                                               b_hh, out, hfin);
    } else {
        __hip_bfloat16* gip = (__hip_bfloat16*)((float*)d_ws + w_u32);
        gemm_gi<__hip_bfloat16><<<ggrid, 256, 0, stream>>>(seq, w_ih, b_ih, gip);
        gru_scan<__hip_bfloat16><<<BB, GG, 0, stream>>>(gip, mask, h0,
                                                        (const uint4*)wf,
                                                        b_hh, out, hfin);
    }
}

// Round 9
// 1786.607 us; speedup vs baseline: 1.3262x; 1.3262x over previous
//
#include <hip/hip_runtime.h>
#include <hip/hip_bf16.h>

#define TT 2048
#define BB 32
#define DD 256
#define HH 256
#define GG 768   // 3*H

typedef _Float16 half2_t __attribute__((ext_vector_type(2)));

__device__ inline float fdot2(unsigned int w, unsigned int h, float acc) {
#if __has_builtin(__builtin_amdgcn_fdot2)
    return __builtin_amdgcn_fdot2(__builtin_bit_cast(half2_t, w),
                                  __builtin_bit_cast(half2_t, h), acc, false);
#else
    half2_t a = __builtin_bit_cast(half2_t, w);
    half2_t b = __builtin_bit_cast(half2_t, h);
    return acc + (float)a.x * (float)b.x + (float)a.y * (float)b.y;
#endif
}

// ---------- helpers for fp32/bf16 workspace storage of gi ----------
__device__ inline void store4(float* p, float a, float b, float c, float d) {
    *(float4*)p = make_float4(a, b, c, d);
}
__device__ inline void store4(__hip_bfloat16* p, float a, float b, float c, float d) {
    p[0] = __float2bfloat16(a);
    p[1] = __float2bfloat16(b);
    p[2] = __float2bfloat16(c);
    p[3] = __float2bfloat16(d);
}
__device__ inline float ldgi(const float* p) { return *p; }
__device__ inline float ldgi(const __hip_bfloat16* p) { return __bfloat162float(*p); }

// ---------- pack w_hh [768][256] f32 -> wpk [128][768] of f16x2 ----------
// wpk[q][j] = (f16(w_hh[j][2q]), f16(w_hh[j][2q+1]))
__global__ __launch_bounds__(256)
void pack_w(const float* __restrict__ w, unsigned int* __restrict__ wpk) {
    int i = blockIdx.x * 256 + threadIdx.x;  // 0 .. 98303
    int q = i / GG;
    int j = i - q * GG;
    float a = w[(size_t)j * DD + 2 * q];
    float b = w[(size_t)j * DD + 2 * q + 1];
    half2_t h = {(_Float16)a, (_Float16)b};
    wpk[i] = __builtin_bit_cast(unsigned int, h);
}

// ---------- gi = seq @ w_ih^T + b_ih ; M=65536, N=768, K=256 ----------
template <typename GiT>
__global__ __launch_bounds__(256)
void gemm_gi(const float* __restrict__ A,     // [M][256]
             const float* __restrict__ W,     // [768][256]
             const float* __restrict__ bias,  // [768]
             GiT* __restrict__ C)              // [M][768]
{
    __shared__ float As[32][68];
    __shared__ float Ws[32][68];
    const int tid = threadIdx.x;
    const int bm = blockIdx.y * 64;
    const int bn = blockIdx.x * 64;
    const int tm = (tid & 15) * 4;
    const int tn = (tid >> 4) * 4;
    const int r  = tid >> 3;
    const int c4 = (tid & 7) * 4;

    float acc[4][4] = {};

    for (int k0 = 0; k0 < 256; k0 += 32) {
#pragma unroll
        for (int rr = 0; rr < 64; rr += 32) {
            float4 a = *(const float4*)&A[(size_t)(bm + r + rr) * 256 + k0 + c4];
            As[c4 + 0][r + rr] = a.x;
            As[c4 + 1][r + rr] = a.y;
            As[c4 + 2][r + rr] = a.z;
            As[c4 + 3][r + rr] = a.w;
            float4 w = *(const float4*)&W[(size_t)(bn + r + rr) * 256 + k0 + c4];
            Ws[c4 + 0][r + rr] = w.x;
            Ws[c4 + 1][r + rr] = w.y;
            Ws[c4 + 2][r + rr] = w.z;
            Ws[c4 + 3][r + rr] = w.w;
        }
        __syncthreads();
#pragma unroll
        for (int kk = 0; kk < 32; ++kk) {
            float4 a = *(const float4*)&As[kk][tm];
            float4 w = *(const float4*)&Ws[kk][tn];
            float av[4] = {a.x, a.y, a.z, a.w};
            float wv[4] = {w.x, w.y, w.z, w.w};
#pragma unroll
            for (int i = 0; i < 4; ++i)
#pragma unroll
                for (int j = 0; j < 4; ++j)
                    acc[i][j] += av[i] * wv[j];
        }
        __syncthreads();
    }
#pragma unroll
    for (int i = 0; i < 4; ++i) {
        GiT* cp = C + (size_t)(bm + tm + i) * GG + bn + tn;
        store4(cp, acc[i][0] + bias[bn + tn + 0],
                   acc[i][1] + bias[bn + tn + 1],
                   acc[i][2] + bias[bn + tn + 2],
                   acc[i][3] + bias[bn + tn + 3]);
    }
}

// ---------- sequential scan: 1 wg per batch row, mask-skip ----------
// EXPERIMENT vs round 4 (one variable): amdgpu_waves_per_eu(3,3) sets the
// allocator's occupancy target to exactly 3 waves/EU (1 block/CU), giving a
// 170-VGPR budget. Rounds 2-8 showed __launch_bounds__'s min-only semantics
// make the allocator target 2 blocks/CU (84 regs for 768 threads) and
// remat/sink all weight loads into the loop (streaming ~384KB/step from L2,
// ~3450 cyc/step vs the 768-cyc VALU floor).
// Thread j holds w_hh row j (256 weights) as 128 packed f16x2 in VGPRs.
template <typename GiT>
__global__ void
__attribute__((amdgpu_flat_work_group_size(768, 768), amdgpu_waves_per_eu(3, 3)))
gru_scan(const GiT* __restrict__ gi,          // [T*B][768]
         const int* __restrict__ mask,         // [T*B]
         const float* __restrict__ h0,         // [B][256]
         const unsigned int* __restrict__ wpk, // [128][768] f16x2
         const float* __restrict__ b_hh,       // [768]
         float* __restrict__ out,              // [T*B][256]
         float* __restrict__ hfin)             // [B][256]
{
    const int b = blockIdx.x;
    const int j = threadIdx.x;  // 0..767
    __shared__ __align__(16) _Float16 hhalf[HH];  // f16 state for the GEMV
    __shared__ float gh_lds[GG];
    __shared__ int mlds[TT];

    // --- one-time: weights into 128 VGPRs (coalesced across lanes) ---
    unsigned int w[128];
#pragma unroll
    for (int q = 0; q < 128; ++q)
        w[q] = wpk[q * GG + j];
#pragma unroll
    for (int q = 0; q < 128; ++q)
        asm volatile("" : "+v"(w[q]));  // discourage rematerialization

    for (int t = j; t < TT; t += GG)
        mlds[t] = mask[t * BB + b];

    float h_r = 0.f;
    if (j < HH) {
        h_r = h0[b * HH + j];
        hhalf[j] = (_Float16)h_r;
    }
    const float bhh = b_hh[j];
    __syncthreads();

    const uint4* hu4 = (const uint4*)hhalf;

    for (int t = 0; t < TT; ++t) {
        if (mlds[t]) {
            // gi loads issued now, consumed in the gate phase (~1000+ cyc
            // later: GEMV + barrier cover HBM latency)
            float ir = 0.f, iz = 0.f, inn = 0.f;
            if (j < HH) {
                const GiT* gtb = gi + ((size_t)t * BB + b) * GG;
                ir  = ldgi(gtb + j);
                iz  = ldgi(gtb + j + HH);
                inn = ldgi(gtb + j + 2 * HH);
            }

            // GEMV: gh[j] = b_hh[j] + sum_k w_hh[j][k] * h[k]
            float a0 = bhh, a1 = 0.f, a2 = 0.f, a3 = 0.f;
#pragma unroll
            for (int q4 = 0; q4 < 32; ++q4) {
                uint4 hv = hu4[q4];  // wave-uniform -> LDS broadcast
                a0 = fdot2(w[4 * q4 + 0], hv.x, a0);
                a1 = fdot2(w[4 * q4 + 1], hv.y, a1);
                a2 = fdot2(w[4 * q4 + 2], hv.z, a2);
                a3 = fdot2(w[4 * q4 + 3], hv.w, a3);
            }
            gh_lds[j] = (a0 + a1) + (a2 + a3);
            __syncthreads();  // gh visible; hhalf reads done

            if (j < HH) {
                float hr = gh_lds[j];
                float hz = gh_lds[j + HH];
                float hn = gh_lds[j + 2 * HH];
                float r = 1.f / (1.f + __expf(-(ir + hr)));
                float z = 1.f / (1.f + __expf(-(iz + hz)));
                float e = __expf(2.f * (inn + r * hn));
                float n = 1.f - 2.f / (e + 1.f);
                float ht = (1.f - z) * n + z * h_r;
                out[((size_t)t * BB + b) * HH + j] = ht;
                h_r = ht;
                hhalf[j] = (_Float16)ht;
            }
            __syncthreads();  // h update visible before next GEMV
        } else {
            // masked step: h unchanged, output row is exactly zero;
            // no GEMV, no gi read, no barriers (branch is block-uniform)
            if (j < HH)
                out[((size_t)t * BB + b) * HH + j] = 0.f;
        }
    }
    if (j < HH) hfin[b * HH + j] = h_r;
}

extern "C" void kernel_launch(void* const* d_in, const int* in_sizes, int n_in,
                              void* d_out, int out_size, void* d_ws, size_t ws_size,
                              hipStream_t stream) {
    const float* seq  = (const float*)d_in[0];
    const int*   mask = (const int*)  d_in[1];
    const float* h0   = (const float*)d_in[2];
    const float* w_ih = (const float*)d_in[3];
    const float* w_hh = (const float*)d_in[4];
    const float* b_ih = (const float*)d_in[5];
    const float* b_hh = (const float*)d_in[6];

    float* out  = (float*)d_out;
    float* hfin = out + (size_t)TT * BB * HH;

    // workspace layout: [wpk: 128*768 u32][gi: T*B*768 f32 (or bf16 fallback)]
    const size_t wpk_elems = (size_t)128 * GG;
    unsigned int* wpk = (unsigned int*)d_ws;
    const size_t gi_elems = (size_t)TT * BB * GG;
    const size_t need_f32 = wpk_elems * 4 + gi_elems * 4;

    pack_w<<<(128 * GG) / 256, 256, 0, stream>>>(w_hh, wpk);

    dim3 ggrid(GG / 64, (TT * BB) / 64);
    if (ws_size >= need_f32) {
        float* gip = (float*)d_ws + wpk_elems;
        gemm_gi<float><<<ggrid, 256, 0, stream>>>(seq, w_ih, b_ih, gip);
        gru_scan<float><<<BB, GG, 0, stream>>>(gip, mask, h0, wpk, b_hh, out, hfin);
    } else {
        __hip_bfloat16* gip = (__hip_bfloat16*)((float*)d_ws + wpk_elems);
        gemm_gi<__hip_bfloat16><<<ggrid, 256, 0, stream>>>(seq, w_ih, b_ih, gip);
        gru_scan<__hip_bfloat16><<<BB, GG, 0, stream>>>(gip, mask, h0, wpk, b_hh, out, hfin);
    }
}

// Round 10
// 1571.522 us; speedup vs baseline: 1.5077x; 1.1369x over previous
//
#include <hip/hip_runtime.h>
#include <hip/hip_bf16.h>

#define TT 2048
#define BB 32
#define DD 256
#define HH 256
#define GG 768   // 3*H

typedef _Float16 half2_t __attribute__((ext_vector_type(2)));
typedef _Float16 f16x8 __attribute__((ext_vector_type(8)));
typedef float    f32x4 __attribute__((ext_vector_type(4)));

__device__ inline float fdot2(unsigned int w, unsigned int h, float acc) {
#if __has_builtin(__builtin_amdgcn_fdot2)
    return __builtin_amdgcn_fdot2(__builtin_bit_cast(half2_t, w),
                                  __builtin_bit_cast(half2_t, h), acc, false);
#else
    half2_t a = __builtin_bit_cast(half2_t, w);
    half2_t b = __builtin_bit_cast(half2_t, h);
    return acc + (float)a.x * (float)b.x + (float)a.y * (float)b.y;
#endif
}

// ---------- helpers for fp32/bf16 workspace storage of gi ----------
__device__ inline float ldgi(const float* p) { return *p; }
__device__ inline float ldgi(const __hip_bfloat16* p) { return __bfloat162float(*p); }
__device__ inline void stgi(float* p, float v) { *p = v; }
__device__ inline void stgi(__hip_bfloat16* p, float v) { *p = __float2bfloat16(v); }

// ---------- pack w_hh [768][256] f32 -> wpk [128][768] of f16x2 ----------
// wpk[q][j] = (f16(w_hh[j][2q]), f16(w_hh[j][2q+1]))
__global__ __launch_bounds__(256)
void pack_w(const float* __restrict__ w, unsigned int* __restrict__ wpk) {
    int i = blockIdx.x * 256 + threadIdx.x;  // 0 .. 98303
    int q = i / GG;
    int j = i - q * GG;
    float a = w[(size_t)j * DD + 2 * q];
    float b = w[(size_t)j * DD + 2 * q + 1];
    half2_t h = {(_Float16)a, (_Float16)b};
    wpk[i] = __builtin_bit_cast(unsigned int, h);
}

// ---------- gi = seq @ w_ih^T + b_ih via f16 MFMA ----------
// M=65536, N=768, K=256. Tile 128x128, BK=32, 4 waves (2x2), 4x4 frags/wave.
// Fragment mapping verified in round 3 (refcheck passed):
//   A/B operand: lane l holds [idx = l&15][k = (l>>4)*8 + i], i=0..7
//   C/D: row = (l>>4)*4 + q, col = l&15
template <typename GiT>
__global__ __launch_bounds__(256)
void gemm_gi_mfma(const float* __restrict__ A,     // [M][256] f32
                  const float* __restrict__ W,     // [768][256] f32
                  const float* __restrict__ bias,  // [768]
                  GiT* __restrict__ C)              // [M][768]
{
    __shared__ __align__(16) _Float16 Asl[128][40];  // 40 = 32 + 8 pad (80B rows)
    __shared__ __align__(16) _Float16 Bsl[128][40];

    const int tid = threadIdx.x;
    const int wv  = tid >> 6;        // 0..3
    const int l   = tid & 63;
    const int wm  = (wv & 1) * 64;   // wave M offset in tile
    const int wn  = (wv >> 1) * 64;  // wave N offset in tile
    const size_t bm = (size_t)blockIdx.y * 128;
    const int    bn = blockIdx.x * 128;

    const int lr = tid >> 3;        // 0..31: staging row group
    const int lc = (tid & 7) * 4;   // 0..28: staging k offset (float4)

    f32x4 acc[4][4] = {};  // [mi][ni]

    for (int kt = 0; kt < 256; kt += 32) {
        // ---- stage A-tile and B-tile (f32 -> f16), 8B packed writes ----
#pragma unroll
        for (int rr = 0; rr < 128; rr += 32) {
            float4 av = *(const float4*)&A[(bm + lr + rr) * DD + kt + lc];
            half2_t p0 = {(_Float16)av.x, (_Float16)av.y};
            half2_t p1 = {(_Float16)av.z, (_Float16)av.w};
            uint2 pk = {__builtin_bit_cast(unsigned int, p0),
                        __builtin_bit_cast(unsigned int, p1)};
            *(uint2*)&Asl[lr + rr][lc] = pk;
        }
#pragma unroll
        for (int rr = 0; rr < 128; rr += 32) {
            float4 bv = *(const float4*)&W[(size_t)(bn + lr + rr) * DD + kt + lc];
            half2_t p0 = {(_Float16)bv.x, (_Float16)bv.y};
            half2_t p1 = {(_Float16)bv.z, (_Float16)bv.w};
            uint2 pk = {__builtin_bit_cast(unsigned int, p0),
                        __builtin_bit_cast(unsigned int, p1)};
            *(uint2*)&Bsl[lr + rr][lc] = pk;
        }
        __syncthreads();

        // ---- fragments + 16 MFMA ----
        f16x8 af[4], bf[4];
#pragma unroll
        for (int i = 0; i < 4; ++i) {
            af[i] = *(const f16x8*)&Asl[wm + i * 16 + (l & 15)][(l >> 4) * 8];
            bf[i] = *(const f16x8*)&Bsl[wn + i * 16 + (l & 15)][(l >> 4) * 8];
        }
#pragma unroll
        for (int mi = 0; mi < 4; ++mi)
#pragma unroll
            for (int ni = 0; ni < 4; ++ni)
                acc[mi][ni] = __builtin_amdgcn_mfma_f32_16x16x32_f16(
                    af[mi], bf[ni], acc[mi][ni], 0, 0, 0);
        __syncthreads();
    }

    // ---- epilogue: C[bm+wm+mi*16+(l>>4)*4+q][bn+wn+ni*16+(l&15)] ----
    const int crow = (l >> 4) * 4;
    const int ccol = l & 15;
#pragma unroll
    for (int ni = 0; ni < 4; ++ni) {
        int n = bn + wn + ni * 16 + ccol;
        float bs = bias[n];
#pragma unroll
        for (int mi = 0; mi < 4; ++mi) {
#pragma unroll
            for (int q = 0; q < 4; ++q) {
                size_t m = bm + wm + mi * 16 + crow + q;
                stgi(&C[m * GG + n], acc[mi][ni][q] + bs);
            }
        }
    }
}

// ---------- sequential scan: 1 wg per batch row, mask-skip ----------
// (unchanged from round 9 / round 4 — at its structural floor: ~3350cyc per
// unmasked step, bound by the ~128B/cyc per-CU weight stream from L2 and
// ~384 uniform LDS broadcasts/step; allocator refuses weight residency.)
template <typename GiT>
__global__ void
__attribute__((amdgpu_flat_work_group_size(768, 768), amdgpu_waves_per_eu(3, 3)))
gru_scan(const GiT* __restrict__ gi,          // [T*B][768]
         const int* __restrict__ mask,         // [T*B]
         const float* __restrict__ h0,         // [B][256]
         const unsigned int* __restrict__ wpk, // [128][768] f16x2
         const float* __restrict__ b_hh,       // [768]
         float* __restrict__ out,              // [T*B][256]
         float* __restrict__ hfin)             // [B][256]
{
    const int b = blockIdx.x;
    const int j = threadIdx.x;  // 0..767
    __shared__ __align__(16) _Float16 hhalf[HH];
    __shared__ float gh_lds[GG];
    __shared__ int mlds[TT];

    unsigned int w[128];
#pragma unroll
    for (int q = 0; q < 128; ++q)
        w[q] = wpk[q * GG + j];
#pragma unroll
    for (int q = 0; q < 128; ++q)
        asm volatile("" : "+v"(w[q]));

    for (int t = j; t < TT; t += GG)
        mlds[t] = mask[t * BB + b];

    float h_r = 0.f;
    if (j < HH) {
        h_r = h0[b * HH + j];
        hhalf[j] = (_Float16)h_r;
    }
    const float bhh = b_hh[j];
    __syncthreads();

    const uint4* hu4 = (const uint4*)hhalf;

    for (int t = 0; t < TT; ++t) {
        if (mlds[t]) {
            float ir = 0.f, iz = 0.f, inn = 0.f;
            if (j < HH) {
                const GiT* gtb = gi + ((size_t)t * BB + b) * GG;
                ir  = ldgi(gtb + j);
                iz  = ldgi(gtb + j + HH);
                inn = ldgi(gtb + j + 2 * HH);
            }

            float a0 = bhh, a1 = 0.f, a2 = 0.f, a3 = 0.f;
#pragma unroll
            for (int q4 = 0; q4 < 32; ++q4) {
                uint4 hv = hu4[q4];  // wave-uniform -> LDS broadcast
                a0 = fdot2(w[4 * q4 + 0], hv.x, a0);
                a1 = fdot2(w[4 * q4 + 1], hv.y, a1);
                a2 = fdot2(w[4 * q4 + 2], hv.z, a2);
                a3 = fdot2(w[4 * q4 + 3], hv.w, a3);
            }
            gh_lds[j] = (a0 + a1) + (a2 + a3);
            __syncthreads();

            if (j < HH) {
                float hr = gh_lds[j];
                float hz = gh_lds[j + HH];
                float hn = gh_lds[j + 2 * HH];
                float r = 1.f / (1.f + __expf(-(ir + hr)));
                float z = 1.f / (1.f + __expf(-(iz + hz)));
                float e = __expf(2.f * (inn + r * hn));
                float n = 1.f - 2.f / (e + 1.f);
                float ht = (1.f - z) * n + z * h_r;
                out[((size_t)t * BB + b) * HH + j] = ht;
                h_r = ht;
                hhalf[j] = (_Float16)ht;
            }
            __syncthreads();
        } else {
            if (j < HH)
                out[((size_t)t * BB + b) * HH + j] = 0.f;
        }
    }
    if (j < HH) hfin[b * HH + j] = h_r;
}

extern "C" void kernel_launch(void* const* d_in, const int* in_sizes, int n_in,
                              void* d_out, int out_size, void* d_ws, size_t ws_size,
                              hipStream_t stream) {
    const float* seq  = (const float*)d_in[0];
    const int*   mask = (const int*)  d_in[1];
    const float* h0   = (const float*)d_in[2];
    const float* w_ih = (const float*)d_in[3];
    const float* w_hh = (const float*)d_in[4];
    const float* b_ih = (const float*)d_in[5];
    const float* b_hh = (const float*)d_in[6];

    float* out  = (float*)d_out;
    float* hfin = out + (size_t)TT * BB * HH;

    // workspace layout: [wpk: 128*768 u32][gi: T*B*768 f32 (or bf16 fallback)]
    const size_t wpk_elems = (size_t)128 * GG;
    unsigned int* wpk = (unsigned int*)d_ws;
    const size_t gi_elems = (size_t)TT * BB * GG;
    const size_t need_f32 = wpk_elems * 4 + gi_elems * 4;

    pack_w<<<(128 * GG) / 256, 256, 0, stream>>>(w_hh, wpk);

    dim3 ggrid(GG / 128, (TT * BB) / 128);  // 6 x 512
    if (ws_size >= need_f32) {
        float* gip = (float*)d_ws + wpk_elems;
        gemm_gi_mfma<float><<<ggrid, 256, 0, stream>>>(seq, w_ih, b_ih, gip);
        gru_scan<float><<<BB, GG, 0, stream>>>(gip, mask, h0, wpk, b_hh, out, hfin);
    } else {
        __hip_bfloat16* gip = (__hip_bfloat16*)((float*)d_ws + wpk_elems);
        gemm_gi_mfma<__hip_bfloat16><<<ggrid, 256, 0, stream>>>(seq, w_ih, b_ih, gip);
        gru_scan<__hip_bfloat16><<<BB, GG, 0, stream>>>(gip, mask, h0, wpk, b_hh, out, hfin);
    }
}